// Round 4
// baseline (279.306 us; speedup 1.0000x reference)
//
#include <hip/hip_runtime.h>
#include <math.h>

// Problem constants: B=8, D=8 (channels), H=256, W=256, M=256
#define HWPIX 65536   // 256*256
#define NMATCH 256
#define THETA_LEN 169

typedef __fp16 h2   __attribute__((ext_vector_type(2)));
typedef __fp16 h8   __attribute__((ext_vector_type(8)));
typedef float  f32x4 __attribute__((ext_vector_type(4)));
typedef unsigned int u32;
typedef u32    u32x4 __attribute__((ext_vector_type(4)));

// tanh-approx GELU in sigmoid form on HW transcendentals (verified passing):
//   gelu(x) ~= x * sigmoid(1.5957691x + 0.0713548x^3)
__device__ __forceinline__ float gelu_fast(float v) {
    float t = fmaf(v * v, 0.10294323f, 2.3022082f);
    float e = __builtin_amdgcn_exp2f(-v * t);
    float r = __builtin_amdgcn_rcpf(1.0f + e);
    return v * r;
}

// pack two f32 -> one dword of 2 f16 (lo = a, hi = b)
__device__ __forceinline__ u32 pkh(float a, float b) {
    return __builtin_bit_cast(u32, __builtin_amdgcn_cvt_pkrtz(a, b));
}
__device__ __forceinline__ h8 mk8(u32 d0, u32 d1, u32 d2, u32 d3) {
    u32x4 t; t[0] = d0; t[1] = d1; t[2] = d2; t[3] = d3;
    return __builtin_bit_cast(h8, t);
}
__device__ __forceinline__ float bperm_f(int addr, float v) {
    return __builtin_bit_cast(float,
        __builtin_amdgcn_ds_bpermute(addr, __builtin_bit_cast(int, v)));
}

// ---------------------------------------------------------------------------
// MFMA kernel. Per wave: one match m, a 2048-px chunk, 128 steps of 16 px.
// Each step: B0(E+rel, f16) -> mfma L0 (bias in C) -> gelu -> bpermute repack
// -> mfma L1 -> gelu -> repack -> mfma L2 -> store row 0.
//
// Fragment layouts (16x16x32 f16, gfx950):
//   A: lane l holds A[m = l&15][k = 8*(l>>4) + e], e=0..7, dword j = (k=2j, 2j+1)
//   B: lane l holds B[k = 8*(l>>4) + e][n = l&15], same dword packing
//   C: lane l holds C[row = 4*(l>>4) + r][col = l&15], r = reg 0..3 (verified m89)
// Rows m>=8 of A are zero -> C rows 8-15 are exactly 0 (finite, gelu-safe).
// K slots >= 10 (L0) / >= 8 (L1, L2) have zero weights -> B content there is
// don't-care (kept finite).
// ---------------------------------------------------------------------------
__global__ __launch_bounds__(256) void dmh_mfma(
    const float* __restrict__ E,        // (8, 8, 256, 256)
    const float* __restrict__ theta,    // (256, 169)
    const float* __restrict__ centers,  // (256, 2)
    const int*   __restrict__ bidx,     // (256,)
    float* __restrict__ out)            // (256, 256, 256)
{
    const int l     = threadIdx.x & 63;
    const int gw    = blockIdx.x * 4 + (threadIdx.x >> 6);  // global wave id
    const int m     = gw >> 5;          // 32 waves per match
    const int chunk = gw & 31;          // 2048-px chunk within match

    const float* __restrict__ th = theta + m * THETA_LEN;
    const float cx = centers[2 * m];
    const float cy = centers[2 * m + 1];
    const int   b  = bidx[m];
    const float* __restrict__ Eb = E + (size_t)b * (8 * HWPIX);

    const int mr = l & 15;   // fragment row (A.m / B.n / C.col)
    const int g  = l >> 4;   // lane group (k-block / row-block)

    // --- A fragments (weights), built once per wave ---
    u32 a0[4], a1[4], a2[4];
    #pragma unroll
    for (int j = 0; j < 4; ++j) {
        const int k0 = 8 * g + 2 * j;
        // L0: W0 is (8 out, 10 in) at th[0:80]
        const float w00 = (mr < 8 && k0     < 10) ? th[mr * 10 + k0]     : 0.f;
        const float w01 = (mr < 8 && k0 + 1 < 10) ? th[mr * 10 + k0 + 1] : 0.f;
        a0[j] = pkh(w00, w01);
        // L1: W1 is (8,8) at th[88:152]; only k<8 (g==0) nonzero
        const float w10 = (mr < 8 && g == 0) ? th[88 + mr * 8 + 2 * j]     : 0.f;
        const float w11 = (mr < 8 && g == 0) ? th[88 + mr * 8 + 2 * j + 1] : 0.f;
        a1[j] = pkh(w10, w11);
        // L2: w2 is (1,8) at th[160:168]; only row 0, k<8
        const float w20 = (mr == 0 && g == 0) ? th[160 + 2 * j]     : 0.f;
        const float w21 = (mr == 0 && g == 0) ? th[160 + 2 * j + 1] : 0.f;
        a2[j] = pkh(w20, w21);
    }
    const h8 A0 = mk8(a0[0], a0[1], a0[2], a0[3]);
    const h8 A1 = mk8(a1[0], a1[1], a1[2], a1[3]);
    const h8 A2 = mk8(a2[0], a2[1], a2[2], a2[3]);

    // --- bias-preloaded accumulator fragments (C row = 4g + r) ---
    f32x4 Cb0, Cb1, Cb2;
    #pragma unroll
    for (int r = 0; r < 4; ++r) {
        const int row = 4 * g + r;
        Cb0[r] = (row < 8) ? th[80 + row]  : 0.f;
        Cb1[r] = (row < 8) ? th[152 + row] : 0.f;
        Cb2[r] = (row == 0) ? th[168]      : 0.f;
    }

    // bpermute addresses: pull C-values of pixel (mr) from lanes mr (rows 0-3)
    // and mr+16 (rows 4-7). addr = 4 * src_lane.
    const int a0addr = 4 * mr;
    const int a1addr = a0addr + 64;

    int p = chunk * 2048 + mr;          // this lane's pixel index
    float* __restrict__ outp = out + (size_t)m * HWPIX;

    for (int step = 0; step < 128; ++step, p += 16) {
        // ---- B0: 8 E channels (k=0..7) + rel (k=8,9 in group 1) ----
        u32 b0[4];
        #pragma unroll
        for (int j = 0; j < 4; ++j)
            b0[j] = pkh(Eb[(size_t)(2 * j) * HWPIX + p],
                        Eb[(size_t)(2 * j + 1) * HWPIX + p]);
        const int   wc = p & 255;
        const int   hr = p >> 8;
        const float rx = (wc + 0.5f) * (1.0f / 256.0f) - cx;
        const float ry = (hr + 0.5f) * (1.0f / 256.0f) - cy;
        const u32 rel = pkh(rx, ry);
        if (g == 1) b0[0] = rel;        // k=8,9
        const f32x4 C0 = __builtin_amdgcn_mfma_f32_16x16x32_f16(
            A0, mk8(b0[0], b0[1], b0[2], b0[3]), Cb0, 0, 0, 0);

        // ---- gelu + repack to B1 (each lane gathers ch0..7 of pixel mr) ----
        float v[8];
        #pragma unroll
        for (int r = 0; r < 4; ++r) {
            const float gv = gelu_fast(C0[r]);
            v[r]     = bperm_f(a0addr, gv);   // ch r   (rows 0-3, lanes 0-15)
            v[4 + r] = bperm_f(a1addr, gv);   // ch 4+r (rows 4-7, lanes 16-31)
        }
        const f32x4 C1 = __builtin_amdgcn_mfma_f32_16x16x32_f16(
            A1, mk8(pkh(v[0], v[1]), pkh(v[2], v[3]),
                    pkh(v[4], v[5]), pkh(v[6], v[7])), Cb1, 0, 0, 0);

        // ---- gelu + repack to B2 ----
        float u[8];
        #pragma unroll
        for (int r = 0; r < 4; ++r) {
            const float gv = gelu_fast(C1[r]);
            u[r]     = bperm_f(a0addr, gv);
            u[4 + r] = bperm_f(a1addr, gv);
        }
        const f32x4 C2 = __builtin_amdgcn_mfma_f32_16x16x32_f16(
            A2, mk8(pkh(u[0], u[1]), pkh(u[2], u[3]),
                    pkh(u[4], u[5]), pkh(u[6], u[7])), Cb2, 0, 0, 0);

        // ---- store: output row 0 lives in lanes 0-15, reg 0 ----
        if (l < 16) outp[p] = C2[0];
    }
}

extern "C" void kernel_launch(void* const* d_in, const int* in_sizes, int n_in,
                              void* d_out, int out_size, void* d_ws, size_t ws_size,
                              hipStream_t stream) {
    const float* E       = (const float*)d_in[0];
    const float* theta   = (const float*)d_in[1];
    const float* centers = (const float*)d_in[2];
    const int*   bidx    = (const int*)d_in[3];
    float* out = (float*)d_out;

    // 256 matches x 32 waves = 8192 waves = 2048 blocks x 4 waves
    dim3 grid(NMATCH * 32 / 4);
    dim3 block(256);
    hipLaunchKernelGGL(dmh_mfma, grid, block, 0, stream, E, theta, centers, bidx, out);
}

// Round 5
// 171.031 us; speedup vs baseline: 1.6331x; 1.6331x over previous
//
#include <hip/hip_runtime.h>
#include <math.h>

// Problem constants: B=8, D=8 (channels), H=256, W=256, M=256
#define HWPIX 65536   // 256*256
#define NMATCH 256
#define THETA_LEN 169
#define TAB_N 1024            // intervals over x in [-8, 8), h = 1/64
#define TAB_BYTES (TAB_N * 8) // float2 per entry

// ---------------------------------------------------------------------------
// Table-fill pre-kernel (runs once, 4 blocks x 256 threads = 1024 entries).
// Entry i covers x in [(i-512)/64, (i-511)/64):
//   v = 64 * gelu_exact(x_i),  d = 64 * (gelu_exact(x_{i+1}) - gelu_exact(x_i))
// gelu_exact = x * 0.5 * (1 + erf(x/sqrt(2)))  -- matches reference (approximate=False).
// Scale 64 folds the next layer's input scaling into the table (see main kernel).
// ---------------------------------------------------------------------------
__device__ __forceinline__ float gelu_exact(float x) {
    return 0.5f * x * (1.0f + erff(x * 0.70710678118654752f));
}

__global__ __launch_bounds__(256) void fill_tab(float2* __restrict__ gtab) {
    const int i = blockIdx.x * 256 + threadIdx.x;
    if (i >= TAB_N) return;
    const float x0 = (i - 512) * (1.0f / 64.0f);
    const float x1 = (i - 511) * (1.0f / 64.0f);
    const float g0 = 64.0f * gelu_exact(x0);
    const float g1 = 64.0f * gelu_exact(x1);
    float2 e; e.x = g0; e.y = g1 - g0;
    gtab[i] = e;
}

// ---------------------------------------------------------------------------
// Main kernel: fp32 FMA matmuls (proven numerics) + LDS-LUT gelu.
//
// Scaling scheme (index map xi = 64*x + 512 folded into the network):
//   - E inputs and rel channels scaled x64 at load.
//   - L0/L1 bias init: a = 64*b + 512  -> accumulator IS the table index xi.
//   - Table emits 64*gelu(x), so L1 consumes it with RAW weights.
//   - L2 weights scaled x(1/64), bias raw -> output unscaled.
// Tails handled exactly: index clamped to [0,1023], frac left unclamped ->
// linear extrapolation reproduces gelu(x)=x (x>8) and 0 (x<-8).
// ---------------------------------------------------------------------------
__device__ __forceinline__ float gelu_lut(float xi, const float2* __restrict__ tab) {
    const float xc = fminf(fmaxf(xi, 0.0f), 1023.0f);  // v_med3_f32
    const int   i  = (int)xc;                          // trunc == floor (xc>=0)
    const float fr = xi - (float)i;                    // unclamped frac
    const float2 t = tab[i];                           // ds_read_b64
    return fmaf(fr, t.y, t.x);                         // 64*gelu
}

__global__ __launch_bounds__(256) void dmh_lut(
    const float* __restrict__ E,        // (8, 8, 256, 256)
    const float* __restrict__ theta,    // (256, 169)
    const float* __restrict__ centers,  // (256, 2)
    const int*   __restrict__ bidx,     // (256,)
    const float2* __restrict__ gtab,    // global gelu table (workspace)
    float* __restrict__ out)            // (256, 256, 256)
{
    __shared__ float2 tab[TAB_N];
    {   // stage table: 512 float4 by 256 threads (2 each)
        const float4* gt = (const float4*)gtab;
        float4* st = (float4*)tab;
        st[threadIdx.x]       = gt[threadIdx.x];
        st[threadIdx.x + 256] = gt[threadIdx.x + 256];
    }
    __syncthreads();

    const int m    = blockIdx.x >> 6;
    const int tile = blockIdx.x & 63;
    const int p0   = tile * 1024 + threadIdx.x * 4;

    const float* __restrict__ th = theta + m * THETA_LEN;   // uniform -> s_load
    const float cx64 = 64.0f * centers[2 * m];
    const float cy64 = 64.0f * centers[2 * m + 1];
    const int   b    = bidx[m];
    const float* __restrict__ Eb = E + (size_t)b * (8 * HWPIX) + p0;

    const int h = p0 >> 8;
    const int w = p0 & 255;   // multiple of 4 -> 4 pixels share h

    // Inputs, pre-scaled x64: 8 E channels + 2 rel channels.
    float x[10][4];
    #pragma unroll
    for (int c = 0; c < 8; ++c) {
        const float4 v = *(const float4*)(Eb + (size_t)c * HWPIX);
        x[c][0] = v.x * 64.0f; x[c][1] = v.y * 64.0f;
        x[c][2] = v.z * 64.0f; x[c][3] = v.w * 64.0f;
    }
    const float ry64 = (h + 0.5f) * 0.25f - cy64;           // 64 * rel_y
    #pragma unroll
    for (int j = 0; j < 4; ++j) {
        x[8][j] = (w + j + 0.5f) * 0.25f - cx64;            // 64 * rel_x
        x[9][j] = ry64;
    }

    // Layer 0: 10 -> 8, raw weights, bias folded to index domain.
    float y[8][4];
    #pragma unroll
    for (int o = 0; o < 8; ++o) {
        const float ainit = fmaf(th[80 + o], 64.0f, 512.0f);
        float a[4] = {ainit, ainit, ainit, ainit};
        #pragma unroll
        for (int i = 0; i < 10; ++i) {
            const float wv = th[o * 10 + i];   // SGPR operand
            #pragma unroll
            for (int j = 0; j < 4; ++j) a[j] = fmaf(wv, x[i][j], a[j]);
        }
        #pragma unroll
        for (int j = 0; j < 4; ++j) y[o][j] = gelu_lut(a[j], tab);  // 64*gelu
    }

    // Layer 1: 8 -> 8, raw weights consume 64-scaled activations.
    float z[8][4];
    #pragma unroll
    for (int o = 0; o < 8; ++o) {
        const float ainit = fmaf(th[152 + o], 64.0f, 512.0f);
        float a[4] = {ainit, ainit, ainit, ainit};
        #pragma unroll
        for (int i = 0; i < 8; ++i) {
            const float wv = th[88 + o * 8 + i];
            #pragma unroll
            for (int j = 0; j < 4; ++j) a[j] = fmaf(wv, y[i][j], a[j]);
        }
        #pragma unroll
        for (int j = 0; j < 4; ++j) z[o][j] = gelu_lut(a[j], tab);  // 64*gelu
    }

    // Layer 2: 8 -> 1, weights x(1/64) to undo activation scale, bias raw.
    const float b2 = th[168];
    float r[4] = {b2, b2, b2, b2};
    #pragma unroll
    for (int i = 0; i < 8; ++i) {
        const float wv = th[160 + i] * (1.0f / 64.0f);
        #pragma unroll
        for (int j = 0; j < 4; ++j) r[j] = fmaf(wv, z[i][j], r[j]);
    }

    float4 o4;
    o4.x = r[0]; o4.y = r[1]; o4.z = r[2]; o4.w = r[3];
    *(float4*)(out + (size_t)m * HWPIX + p0) = o4;
}

// ---------------------------------------------------------------------------
// Fallback: verified fp32 kernel with transcendental gelu (if ws too small).
// ---------------------------------------------------------------------------
__device__ __forceinline__ float gelu_fast(float v) {
    float t = fmaf(v * v, 0.10294323f, 2.3022082f);
    float e = __builtin_amdgcn_exp2f(-v * t);
    float r = __builtin_amdgcn_rcpf(1.0f + e);
    return v * r;
}

__global__ __launch_bounds__(256) void dmh_kernel_f32(
    const float* __restrict__ E,
    const float* __restrict__ theta,
    const float* __restrict__ centers,
    const int*   __restrict__ bidx,
    float* __restrict__ out)
{
    const int m    = blockIdx.x >> 6;
    const int tile = blockIdx.x & 63;
    const int p0   = tile * 1024 + threadIdx.x * 4;

    const float* __restrict__ th = theta + m * THETA_LEN;
    const float cx = centers[2 * m];
    const float cy = centers[2 * m + 1];
    const int   b  = bidx[m];
    const float* __restrict__ Eb = E + (size_t)b * (8 * HWPIX) + p0;

    const int h = p0 >> 8;
    const int w = p0 & 255;

    float x[10][4];
    #pragma unroll
    for (int c = 0; c < 8; ++c) {
        const float4 v = *(const float4*)(Eb + (size_t)c * HWPIX);
        x[c][0] = v.x; x[c][1] = v.y; x[c][2] = v.z; x[c][3] = v.w;
    }
    #pragma unroll
    for (int j = 0; j < 4; ++j) {
        x[8][j] = (w + j + 0.5f) * (1.0f / 256.0f) - cx;
        x[9][j] = (h + 0.5f) * (1.0f / 256.0f) - cy;
    }

    float y[8][4];
    #pragma unroll
    for (int o = 0; o < 8; ++o) {
        const float bias = th[80 + o];
        float a[4] = {bias, bias, bias, bias};
        #pragma unroll
        for (int i = 0; i < 10; ++i) {
            const float wv = th[o * 10 + i];
            #pragma unroll
            for (int j = 0; j < 4; ++j) a[j] = fmaf(wv, x[i][j], a[j]);
        }
        #pragma unroll
        for (int j = 0; j < 4; ++j) y[o][j] = gelu_fast(a[j]);
    }

    float z[8][4];
    #pragma unroll
    for (int o = 0; o < 8; ++o) {
        const float bias = th[152 + o];
        float a[4] = {bias, bias, bias, bias};
        #pragma unroll
        for (int i = 0; i < 8; ++i) {
            const float wv = th[88 + o * 8 + i];
            #pragma unroll
            for (int j = 0; j < 4; ++j) a[j] = fmaf(wv, y[i][j], a[j]);
        }
        #pragma unroll
        for (int j = 0; j < 4; ++j) z[o][j] = gelu_fast(a[j]);
    }

    const float b2 = th[168];
    float r[4] = {b2, b2, b2, b2};
    #pragma unroll
    for (int i = 0; i < 8; ++i) {
        const float wv = th[160 + i];
        #pragma unroll
        for (int j = 0; j < 4; ++j) r[j] = fmaf(wv, z[i][j], r[j]);
    }

    float4 o4;
    o4.x = r[0]; o4.y = r[1]; o4.z = r[2]; o4.w = r[3];
    *(float4*)(out + (size_t)m * HWPIX + p0) = o4;
}

extern "C" void kernel_launch(void* const* d_in, const int* in_sizes, int n_in,
                              void* d_out, int out_size, void* d_ws, size_t ws_size,
                              hipStream_t stream) {
    const float* E       = (const float*)d_in[0];
    const float* theta   = (const float*)d_in[1];
    const float* centers = (const float*)d_in[2];
    const int*   bidx    = (const int*)d_in[3];
    float* out = (float*)d_out;

    if (ws_size >= (size_t)TAB_BYTES && d_ws != nullptr) {
        float2* gtab = (float2*)d_ws;
        hipLaunchKernelGGL(fill_tab, dim3(4), dim3(256), 0, stream, gtab);
        hipLaunchKernelGGL(dmh_lut, dim3(NMATCH * 64), dim3(256), 0, stream,
                           E, theta, centers, bidx, gtab, out);
    } else {
        hipLaunchKernelGGL(dmh_kernel_f32, dim3(NMATCH * 64), dim3(256), 0, stream,
                           E, theta, centers, bidx, out);
    }
}